// Round 5
// baseline (375.673 us; speedup 1.0000x reference)
//
#include <hip/hip_runtime.h>

#define BATCH 8192
#define FEATURE_NUM 200
#define NUMERIC_SIZE 100
#define IN_STRIDE (FEATURE_NUM + NUMERIC_SIZE)  // 300
#define EMBED 64
#define WAVES_PER_BLOCK 4

// One wave per batch row. Lane split: sub = lane>>4 (feature subgroup 0..3),
// l = lane&15 (dim quarter -> dims 4l..4l+3). Each global_load_dwordx4
// fetches 4 embedding rows (1 KB) per instruction: 50 gather instructions
// per wave instead of 200 (tests the VMEM-slot-pressure hypothesis).
// float4 accumulators are butterfly-combined across subgroups (shfl_xor
// 16,32) before the FM squaring; only sub==0 lanes contribute it.

__device__ __forceinline__ void load4(const float4* __restrict__ vtab,
                                      const int* sidx, int base, int sub,
                                      int l, float4 vv[4]) {
    #pragma unroll
    for (int i = 0; i < 4; ++i) {
        int idx = sidx[base + i * 4 + sub];          // wave-uniform broadcast
        vv[i] = vtab[(size_t)idx * 16 + l];          // 16B/lane, 4 rows/inst
    }
}

__device__ __forceinline__ void acc4(const float4 vv[4],
                                     float4& fs, float4& fss) {
    #pragma unroll
    for (int i = 0; i < 4; ++i) {
        fs.x += vv[i].x; fss.x += vv[i].x * vv[i].x;
        fs.y += vv[i].y; fss.y += vv[i].y * vv[i].y;
        fs.z += vv[i].z; fss.z += vv[i].z * vv[i].z;
        fs.w += vv[i].w; fss.w += vv[i].w * vv[i].w;
    }
}

__global__ __launch_bounds__(256, 8) void fm_layer_kernel(
    const float* __restrict__ inputs,      // (B, 300)
    const float* __restrict__ w_one_hot,   // (1e6, 1)
    const float* __restrict__ w_numeric,   // (100, 1)
    const float* __restrict__ v_one_hot,   // (1e6, 64)
    const float* __restrict__ v_numeric,   // (100, 64)
    const float* __restrict__ bias,        // (1,)
    float* __restrict__ out)               // (B, 1)
{
    __shared__ int   s_idx[WAVES_PER_BLOCK][FEATURE_NUM];
    __shared__ float s_num[WAVES_PER_BLOCK][NUMERIC_SIZE];

    const int lane = threadIdx.x & 63;
    const int wave = threadIdx.x >> 6;
    const int sub  = lane >> 4;     // feature subgroup
    const int l    = lane & 15;     // dim quarter
    const int row  = blockIdx.x * WAVES_PER_BLOCK + wave;

    const float* in_row = inputs + (size_t)row * IN_STRIDE;

    // coalesced staging of this row's 300 floats; indices -> int once
    for (int j = lane; j < IN_STRIDE; j += 64) {
        float x = in_row[j];
        if (j < FEATURE_NUM) s_idx[wave][j] = (int)x;
        else                 s_num[wave][j - FEATURE_NUM] = x;
    }
    __syncthreads();

    const int*   sidx = s_idx[wave];
    const float* snum = s_num[wave];
    const float4* vtab = (const float4*)v_one_hot;   // 16 float4 per row
    const float4* ntab = (const float4*)v_numeric;

    float4 fs4  = {0.f, 0.f, 0.f, 0.f};
    float4 fss4 = {0.f, 0.f, 0.f, 0.f};

    // ---- pipelined one-hot gathers: 12 chunks of 4 insts (16 features) ----
    float4 va[4], vb[4];
    load4(vtab, sidx, 0, sub, l, va);                // chunk 0: features 0-15

    // numeric second-order overlaps chunk-0 latency (v_numeric L1-resident)
    #pragma unroll 1
    for (int jj = 0; jj < 25; jj += 5) {
        #pragma unroll
        for (int t = 0; t < 5; ++t) {
            int j = (jj + t) * 4 + sub;
            float  x = snum[j];
            float4 v = ntab[(size_t)j * 16 + l];
            float nx = x * v.x, ny = x * v.y, nz = x * v.z, nw = x * v.w;
            fs4.x += nx; fss4.x += nx * nx;
            fs4.y += ny; fss4.y += ny * ny;
            fs4.z += nz; fss4.z += nz * nz;
            fs4.w += nw; fss4.w += nw * nw;
        }
    }

    #pragma unroll 1
    for (int k = 0; k < 5; ++k) {
        load4(vtab, sidx, (2 * k + 1) * 16, sub, l, vb);
        acc4(va, fs4, fss4);
        load4(vtab, sidx, (2 * k + 2) * 16, sub, l, va);
        acc4(vb, fs4, fss4);
    }
    load4(vtab, sidx, 11 * 16, sub, l, vb);          // chunk 11: 176-191
    acc4(va, fs4, fss4);                             // chunk 10
    float4 t0, t1;                                   // tail: features 192-199
    { int i0 = sidx[192 + sub]; t0 = vtab[(size_t)i0 * 16 + l];
      int i1 = sidx[196 + sub]; t1 = vtab[(size_t)i1 * 16 + l]; }
    acc4(vb, fs4, fss4);                             // chunk 11
    fs4.x += t0.x + t1.x; fss4.x += t0.x * t0.x + t1.x * t1.x;
    fs4.y += t0.y + t1.y; fss4.y += t0.y * t0.y + t1.y * t1.y;
    fs4.z += t0.z + t1.z; fss4.z += t0.z * t0.z + t1.z * t1.z;
    fs4.w += t0.w + t1.w; fss4.w += t0.w * t0.w + t1.w * t1.w;

    // ---- combine feature subgroups: butterfly over lanes l, l+16, l+32, l+48
    #pragma unroll
    for (int off = 16; off <= 32; off <<= 1) {
        fs4.x  += __shfl_xor(fs4.x,  off, 64);
        fs4.y  += __shfl_xor(fs4.y,  off, 64);
        fs4.z  += __shfl_xor(fs4.z,  off, 64);
        fs4.w  += __shfl_xor(fs4.w,  off, 64);
        fss4.x += __shfl_xor(fss4.x, off, 64);
        fss4.y += __shfl_xor(fss4.y, off, 64);
        fss4.z += __shfl_xor(fss4.z, off, 64);
        fss4.w += __shfl_xor(fss4.w, off, 64);
    }

    float so4 = 0.5f * ((fs4.x * fs4.x - fss4.x) + (fs4.y * fs4.y - fss4.y) +
                        (fs4.z * fs4.z - fss4.z) + (fs4.w * fs4.w - fss4.w));
    float partial = (sub == 0) ? so4 : 0.f;   // each dim counted once

    // ---- first-order (w_one_hot: 4 MB, mostly L2; issued post-loop) ----
    partial += w_one_hot[sidx[lane]];
    partial += w_one_hot[sidx[lane + 64]];
    partial += w_one_hot[sidx[lane + 128]];
    if (lane < 8) partial += w_one_hot[sidx[192 + lane]];
    partial += snum[lane] * w_numeric[lane];
    if (lane < NUMERIC_SIZE - 64) partial += snum[lane + 64] * w_numeric[lane + 64];

    // ---- wave64 reduction ----
    #pragma unroll
    for (int off = 32; off > 0; off >>= 1)
        partial += __shfl_down(partial, off, 64);

    if (lane == 0) out[row] = partial + bias[0];
}

extern "C" void kernel_launch(void* const* d_in, const int* in_sizes, int n_in,
                              void* d_out, int out_size, void* d_ws, size_t ws_size,
                              hipStream_t stream) {
    const float* inputs    = (const float*)d_in[0];
    const float* w_one_hot = (const float*)d_in[1];
    const float* w_numeric = (const float*)d_in[2];
    const float* v_one_hot = (const float*)d_in[3];
    const float* v_numeric = (const float*)d_in[4];
    const float* bias      = (const float*)d_in[5];
    float* out = (float*)d_out;

    dim3 grid(BATCH / WAVES_PER_BLOCK);
    dim3 block(256);
    fm_layer_kernel<<<grid, block, 0, stream>>>(
        inputs, w_one_hot, w_numeric, v_one_hot, v_numeric, bias, out);
}